// Round 2
// baseline (2757.891 us; speedup 1.0000x reference)
//
#include <hip/hip_runtime.h>
#include <stdint.h>

#define NN 50000
#define EE 800000
#define BG 2000
#define EMB 300
#define HP 320
#define YP 640
#define MPAD 50048
#define MHEAD 2048
#define NLAYER 5

typedef __attribute__((ext_vector_type(8))) _Float16 f16x8;
typedef __attribute__((ext_vector_type(4))) float f32x4;

__device__ __forceinline__ _Float16 f2h(float f) { return (_Float16)f; }
__device__ __forceinline__ float h2f(_Float16 h) { return (float)h; }

// ---------- weight transpose+convert: dst[Np][Kp] (f16) = src[K][Ns]^T, zero pad
__global__ void k_tconv(const float* __restrict__ src, int K, int Ns,
                        _Float16* __restrict__ dst, int Kp, int Np) {
    int total = Kp * Np;
    for (int idx = blockIdx.x * blockDim.x + threadIdx.x; idx < total;
         idx += gridDim.x * blockDim.x) {
        int n = idx / Kp, k = idx - n * Kp;
        float v = (n < Ns && k < K) ? src[(size_t)k * Ns + n] : 0.f;
        dst[idx] = f2h(v);
    }
}

__global__ void k_padbias(const float* __restrict__ src, int Ns, float* __restrict__ dst, int Np) {
    int i = blockIdx.x * blockDim.x + threadIdx.x;
    if (i < Np) dst[i] = (i < Ns) ? src[i] : 0.f;
}

// ---------- node embedding: h[i][c] = ae1[x0] + ae2[x1] + x[2:]@aw3 + ab3  (f32)
__global__ __launch_bounds__(320) void k_embed(const int* __restrict__ x,
        const float* __restrict__ ae1, const float* __restrict__ ae2,
        const float* __restrict__ aw3, const float* __restrict__ ab3,
        float* __restrict__ h) {
    int i = blockIdx.x, tid = threadIdx.x;
    __shared__ int sx[42];
    if (tid < 42) sx[tid] = x[(size_t)i * 42 + tid];
    __syncthreads();
    if (tid < EMB) {
        float v = ab3[tid] + ae1[(size_t)sx[0] * EMB + tid] + ae2[(size_t)sx[1] * EMB + tid];
        #pragma unroll 8
        for (int j = 0; j < 40; j++) v += (float)sx[2 + j] * aw3[(size_t)j * EMB + tid];
        h[(size_t)i * EMB + tid] = v;
    }
}

// ---------- per-node edge-attr stats (layer-independent)
// stat[i][0..5]=cnt(ea0), [6..9]=cnt(ea1), [10..17]=sum(eaf), [18]=deg incl self
__global__ void k_init(int* __restrict__ stat, int* __restrict__ cursor) {
    int i = blockIdx.x * blockDim.x + threadIdx.x;
    if (i < NN) {
        int* s = stat + (size_t)i * 20;
        #pragma unroll
        for (int k = 0; k < 20; k++) s[k] = 0;
        s[4] = 1;   // self-loop: ea0 = 4
        s[6] = 1;   // self-loop: ea1 = 0
        s[18] = 1;  // deg incl self-loop
        cursor[i] = 0;
    }
}

__global__ void k_estats(const int* __restrict__ ei, const int* __restrict__ ea,
                         int* __restrict__ stat) {
    int e = blockIdx.x * blockDim.x + threadIdx.x;
    if (e < EE) {
        int d = ei[EE + e];
        int* s = stat + (size_t)d * 20;
        atomicAdd(&s[ea[e * 10 + 0]], 1);
        atomicAdd(&s[6 + ea[e * 10 + 1]], 1);
        #pragma unroll
        for (int j = 0; j < 8; j++) {
            int v = ea[e * 10 + 2 + j];
            if (v) atomicAdd(&s[10 + j], v);
        }
        atomicAdd(&s[18], 1);
    }
}

// ---------- exclusive scan of real in-degree (deg-1) -> rowptr
__global__ __launch_bounds__(1024) void k_scan(const int* __restrict__ stat,
                                               int* __restrict__ rowptr) {
    __shared__ int part[1024];
    int t = threadIdx.x;
    const int chunk = (NN + 1023) / 1024;
    int i0 = t * chunk;
    int i1 = min(i0 + chunk, NN);
    int s = 0;
    for (int i = i0; i < i1; i++) s += stat[(size_t)i * 20 + 18] - 1;
    part[t] = s;
    __syncthreads();
    for (int off = 1; off < 1024; off <<= 1) {
        int v = part[t];
        int u = (t >= off) ? part[t - off] : 0;
        __syncthreads();
        part[t] = v + u;
        __syncthreads();
    }
    int run = (t > 0) ? part[t - 1] : 0;
    for (int i = i0; i < i1; i++) { rowptr[i] = run; run += stat[(size_t)i * 20 + 18] - 1; }
    if (t == 1023) rowptr[NN] = part[1023];
}

__global__ void k_fill(const int* __restrict__ ei, const int* __restrict__ rowptr,
                       int* __restrict__ cursor, int* __restrict__ col) {
    int e = blockIdx.x * blockDim.x + threadIdx.x;
    if (e < EE) {
        int d = ei[EE + e];
        int pos = rowptr[d] + atomicAdd(&cursor[d], 1);
        col[pos] = ei[e];
    }
}

// ---------- message aggregation: agg[i] = const(stat,tables) + h[i] + sum_{in} h[src]
// h is f32 [NN][EMB]; agg is f16 [MPAD][HP] (GEMM1 input)
#define AGG_CHUNK 160
__global__ __launch_bounds__(320) void k_agg(const float* __restrict__ h,
        const int* __restrict__ stat, const int* __restrict__ rowptr,
        const int* __restrict__ col,
        const float* __restrict__ ee1, const float* __restrict__ ee2,
        const float* __restrict__ ew3, const float* __restrict__ eb3,
        _Float16* __restrict__ agg, int layer) {
    int i = blockIdx.x;
    int tid = threadIdx.x;
    if (i >= NN) { agg[(size_t)i * HP + tid] = (_Float16)0.f; return; }
    __shared__ int ss[20];
    __shared__ int sc[AGG_CHUNK];
    if (tid < 20) ss[tid] = stat[(size_t)i * 20 + tid];
    __syncthreads();
    float acc = 0.f;
    int c = tid;
    bool act = c < EMB;
    if (act) {
        const float* e1 = ee1 + (size_t)layer * 6 * EMB;
        const float* e2 = ee2 + (size_t)layer * 4 * EMB;
        const float* w3 = ew3 + (size_t)layer * 8 * EMB;
        float v = eb3[(size_t)layer * EMB + c] * (float)ss[18];
        #pragma unroll
        for (int k = 0; k < 6; k++) v += (float)ss[k] * e1[k * EMB + c];
        #pragma unroll
        for (int k = 0; k < 4; k++) v += (float)ss[6 + k] * e2[k * EMB + c];
        #pragma unroll
        for (int j = 0; j < 8; j++) v += (float)ss[10 + j] * w3[j * EMB + c];
        acc = v + h[(size_t)i * EMB + c];
    }
    int beg = rowptr[i], end = rowptr[i + 1];
    for (int e0 = beg; e0 < end; e0 += AGG_CHUNK) {
        int m = min(AGG_CHUNK, end - e0);
        __syncthreads();
        if (tid < m) sc[tid] = col[e0 + tid];
        __syncthreads();
        if (act) {
            for (int e = 0; e < m; e++)
                acc += h[(size_t)sc[e] * EMB + c];
        }
    }
    agg[(size_t)i * HP + tid] = act ? f2h(acc) : (_Float16)0.f;
}

// ---------- f16 MFMA GEMM: C = act(A[M][lda] @ Wt^T + bias)
// Wt is [Npad][Kpad] (pre-transposed). Tile 128x64, 4 waves, K-step 32.
// act: 0=none 1=relu 2=softplus. If Cf != nullptr write f32 there, else f16 to C.
__global__ __launch_bounds__(256) void k_gemm(const _Float16* __restrict__ A, int lda,
        const _Float16* __restrict__ Wt, int ldw, const float* __restrict__ bias,
        _Float16* __restrict__ C, float* __restrict__ Cf, int ldc, int K, int act) {
    __shared__ _Float16 As[128 * 32];
    __shared__ _Float16 Bs[64 * 32];
    int tid = threadIdx.x;
    int lane = tid & 63;
    int wid = tid >> 6;
    int wr = wid >> 1, wc = wid & 1;
    size_t rowBase = (size_t)blockIdx.x * 128;
    int colBase = blockIdx.y * 64;

    int srow = tid >> 2;        // 0..63
    int schunk = tid & 3;       // 16B chunk within 32-elem K-slice
    const _Float16* Ab  = A + (rowBase + srow) * (size_t)lda + (schunk << 3);
    const _Float16* Ab2 = Ab + (size_t)64 * lda;
    const _Float16* Bb  = Wt + ((size_t)colBase + srow) * ldw + (schunk << 3);
    int swz = ((schunk ^ ((srow >> 1) & 3)) << 3);
    int wa0 = srow * 32 + swz;
    int wa1 = wa0 + 64 * 32;   // (srow+64)>>1 & 3 == (srow>>1)&3
    int wb  = wa0;

    uint4 ra0 = *(const uint4*)Ab;
    uint4 ra1 = *(const uint4*)Ab2;
    uint4 rb  = *(const uint4*)Bb;

    int lr = lane & 15, lg = lane >> 4;
    int lswz = (lr >> 1) & 3;
    int aoff[4], boff[2];
    #pragma unroll
    for (int m = 0; m < 4; m++) { int r = wr * 64 + m * 16 + lr; aoff[m] = r * 32 + ((lg ^ lswz) << 3); }
    #pragma unroll
    for (int n = 0; n < 2; n++) { int r = wc * 32 + n * 16 + lr; boff[n] = r * 32 + ((lg ^ lswz) << 3); }

    f32x4 acc[4][2];
    #pragma unroll
    for (int m = 0; m < 4; m++) {
        #pragma unroll
        for (int n = 0; n < 2; n++) acc[m][n] = (f32x4){0.f, 0.f, 0.f, 0.f};
    }

    int nk = K >> 5;
    for (int kt = 0; kt < nk; ++kt) {
        __syncthreads();
        *(uint4*)&As[wa0] = ra0;
        *(uint4*)&As[wa1] = ra1;
        *(uint4*)&Bs[wb]  = rb;
        __syncthreads();
        if (kt + 1 < nk) {
            int o = (kt + 1) << 5;
            ra0 = *(const uint4*)(Ab + o);
            ra1 = *(const uint4*)(Ab2 + o);
            rb  = *(const uint4*)(Bb + o);
        }
        f16x8 af[4], bfr[2];
        #pragma unroll
        for (int m = 0; m < 4; m++) af[m] = *(const f16x8*)&As[aoff[m]];
        #pragma unroll
        for (int n = 0; n < 2; n++) bfr[n] = *(const f16x8*)&Bs[boff[n]];
        #pragma unroll
        for (int m = 0; m < 4; m++) {
            #pragma unroll
            for (int n = 0; n < 2; n++)
                acc[m][n] = __builtin_amdgcn_mfma_f32_16x16x32_f16(af[m], bfr[n], acc[m][n], 0, 0, 0);
        }
    }

    #pragma unroll
    for (int m = 0; m < 4; m++) {
        #pragma unroll
        for (int n = 0; n < 2; n++) {
            int colg = colBase + wc * 32 + n * 16 + lr;
            float bv = bias[colg];
            #pragma unroll
            for (int r = 0; r < 4; r++) {
                size_t rowg = rowBase + wr * 64 + m * 16 + lg * 4 + r;
                float v = acc[m][n][r] + bv;
                if (act == 1) v = fmaxf(v, 0.f);
                else if (act == 2) v = (v > 0.f) ? v + log1pf(expf(-v)) : log1pf(expf(v));
                if (Cf) Cf[rowg * ldc + colg] = v;
                else    C[rowg * ldc + colg] = f2h(v);
            }
        }
    }
}

// ---------- batchnorm (reads f32 h2 [MPAD][HP])
__global__ __launch_bounds__(320) void k_bn_stats(const float* __restrict__ h2,
        float* __restrict__ psum, float* __restrict__ psq) {
    int b = blockIdx.x, tid = threadIdx.x;
    const int rows = (NN + 255) / 256;
    int r0 = b * rows;
    int r1 = min(r0 + rows, NN);
    float s = 0.f, q = 0.f;
    if (tid < EMB) {
        for (int i = r0; i < r1; i++) { float v = h2[(size_t)i * HP + tid]; s += v; q += v * v; }
    }
    psum[(size_t)b * HP + tid] = s;
    psq[(size_t)b * HP + tid] = q;
}

__global__ __launch_bounds__(320) void k_bn_final(const float* __restrict__ psum,
        const float* __restrict__ psq, const float* __restrict__ bng,
        const float* __restrict__ bnb, float* __restrict__ scl, float* __restrict__ sft,
        int layer) {
    int c = threadIdx.x;
    float s = 0.f, q = 0.f;
    for (int b = 0; b < 256; b++) { s += psum[(size_t)b * HP + c]; q += psq[(size_t)b * HP + c]; }
    if (c < EMB) {
        float mu = s / (float)NN;
        float var = q / (float)NN - mu * mu;
        float rstd = rsqrtf(var + 1e-5f);
        float g = bng[(size_t)layer * EMB + c] * rstd;
        scl[c] = g;
        sft[c] = bnb[(size_t)layer * EMB + c] - mu * g;
    } else { scl[c] = 0.f; sft[c] = 0.f; }
}

// reads f32 h2, writes f32 h [NN][EMB] (next-layer gather src) or f32 out
__global__ __launch_bounds__(320) void k_bn_apply(const float* __restrict__ h2,
        const float* __restrict__ scl, const float* __restrict__ sft,
        float* __restrict__ hout, int relu) {
    int i = blockIdx.x, c = threadIdx.x;
    if (c < EMB) {
        float v = h2[(size_t)i * HP + c] * scl[c] + sft[c];
        if (relu) v = fmaxf(v, 0.f);
        hout[(size_t)i * EMB + c] = v;
    }
}

// ---------- pooling + head
__global__ void k_pool_init(float* __restrict__ pooled, int* __restrict__ cntB) {
    int i = blockIdx.x * blockDim.x + threadIdx.x;
    if (i < BG * EMB) pooled[i] = 0.f;
    if (i < BG) cntB[i] = 0;
}

__global__ __launch_bounds__(320) void k_pool_acc(const float* __restrict__ hn,
        const int* __restrict__ batch, float* __restrict__ pooled, int* __restrict__ cntB) {
    int i = blockIdx.x, c = threadIdx.x;
    int b = batch[i];
    if (c < EMB) atomicAdd(&pooled[(size_t)b * EMB + c], hn[(size_t)i * EMB + c]);
    if (c == EMB) atomicAdd(&cntB[b], 1);
}

__global__ __launch_bounds__(512) void k_head_in(const float* __restrict__ pooled,
        const int* __restrict__ cntB, const float* __restrict__ x_add,
        _Float16* __restrict__ hin) {
    int b = blockIdx.x, c = threadIdx.x;
    float v = 0.f;
    if (b < BG) {
        if (c < EMB) {
            float inv = 1.f / (float)max(cntB[b], 1);
            v = pooled[(size_t)b * EMB + c] * inv;
        } else if (c < EMB + 200) {
            v = x_add[(size_t)b * 200 + (c - EMB)];
        }
    }
    hin[(size_t)b * 512 + c] = f2h(v);
}

__global__ __launch_bounds__(64) void k_pred(const _Float16* __restrict__ g3,
        const float* __restrict__ pw3, const float* __restrict__ pb3, float* __restrict__ out) {
    int row = blockIdx.x;
    int lane = threadIdx.x;
    float s = 0.f;
    #pragma unroll
    for (int t = 0; t < 4; t++) {
        int k = lane * 4 + t;
        s += h2f(g3[(size_t)row * 256 + k]) * pw3[k];
    }
    #pragma unroll
    for (int off = 32; off; off >>= 1) s += __shfl_down(s, off);
    if (lane == 0) out[row] = s + pb3[0];
}

extern "C" void kernel_launch(void* const* d_in, const int* in_sizes, int n_in,
                              void* d_out, int out_size, void* d_ws, size_t ws_size,
                              hipStream_t stream) {
    const int*   x     = (const int*)d_in[0];
    const int*   ei    = (const int*)d_in[1];
    const int*   ea    = (const int*)d_in[2];
    const int*   batch = (const int*)d_in[3];
    const float* x_add = (const float*)d_in[4];
    const float* ae1   = (const float*)d_in[5];
    const float* ae2   = (const float*)d_in[6];
    const float* aw3   = (const float*)d_in[7];
    const float* ab3   = (const float*)d_in[8];
    const float* ee1   = (const float*)d_in[9];
    const float* ee2   = (const float*)d_in[10];
    const float* ew3   = (const float*)d_in[11];
    const float* eb3   = (const float*)d_in[12];
    const float* mw1   = (const float*)d_in[13];
    const float* mb1   = (const float*)d_in[14];
    const float* mw2   = (const float*)d_in[15];
    const float* mb2   = (const float*)d_in[16];
    const float* bng   = (const float*)d_in[17];
    const float* bnb   = (const float*)d_in[18];
    const float* fw    = (const float*)d_in[19];
    const float* fb    = (const float*)d_in[20];
    const float* pw1   = (const float*)d_in[21];
    const float* pb1   = (const float*)d_in[22];
    const float* pw2   = (const float*)d_in[23];
    const float* pb2   = (const float*)d_in[24];
    const float* pw3   = (const float*)d_in[25];
    const float* pb3   = (const float*)d_in[26];
    (void)in_sizes; (void)n_in; (void)out_size; (void)ws_size;
    float* out = (float*)d_out;

    char* p = (char*)d_ws;
    auto take = [&](size_t bytes) -> char* {
        char* r = p; p += (bytes + 255) & ~(size_t)255; return r;
    };
    float*     h    = (float*)take((size_t)NN * EMB * 4);
    _Float16*  agg  = (_Float16*)take((size_t)MPAD * HP * 2);
    _Float16*  y1   = (_Float16*)take((size_t)MPAD * YP * 2);
    float*     h2f  = (float*)take((size_t)MPAD * HP * 4);
    _Float16*  w1t  = (_Float16*)take((size_t)NLAYER * YP * HP * 2);
    _Float16*  w2t  = (_Float16*)take((size_t)NLAYER * HP * YP * 2);
    _Float16*  fwt  = (_Float16*)take((size_t)512 * 512 * 2);
    _Float16*  p1t  = (_Float16*)take((size_t)256 * 512 * 2);
    _Float16*  p2t  = (_Float16*)take((size_t)256 * 256 * 2);
    float* b1p   = (float*)take((size_t)NLAYER * YP * 4);
    float* b2p   = (float*)take((size_t)NLAYER * HP * 4);
    int* stat    = (int*)take((size_t)NN * 20 * 4);
    int* cursor  = (int*)take((size_t)NN * 4);
    int* rowptr  = (int*)take((size_t)(NN + 1) * 4);
    int* col     = (int*)take((size_t)EE * 4);
    float* psum  = (float*)take((size_t)256 * HP * 4);
    float* psq   = (float*)take((size_t)256 * HP * 4);
    float* scl   = (float*)take((size_t)HP * 4);
    float* sft   = (float*)take((size_t)HP * 4);
    float* pooled = (float*)take((size_t)BG * EMB * 4);
    int* cntB    = (int*)take((size_t)BG * 4);
    // head buffers alias y1's space (y1 dead after the layer loop)
    char* hb = (char*)y1;
    _Float16* hin = (_Float16*)hb;               hb += (size_t)MHEAD * 512 * 2;
    _Float16* g1  = (_Float16*)hb;               hb += (size_t)MHEAD * 512 * 2;
    _Float16* g2  = (_Float16*)hb;               hb += (size_t)MHEAD * 256 * 2;
    _Float16* g3  = (_Float16*)hb;

    // weight conversion (transposed f16 + padded biases)
    for (int l = 0; l < NLAYER; l++) {
        k_tconv<<<208, 256, 0, stream>>>(mw1 + (size_t)l * EMB * 2 * EMB, EMB, 2 * EMB,
                                         w1t + (size_t)l * YP * HP, HP, YP);
        k_tconv<<<208, 256, 0, stream>>>(mw2 + (size_t)l * 2 * EMB * EMB, 2 * EMB, EMB,
                                         w2t + (size_t)l * HP * YP, YP, HP);
        k_padbias<<<3, 256, 0, stream>>>(mb1 + (size_t)l * 2 * EMB, 2 * EMB, b1p + (size_t)l * YP, YP);
        k_padbias<<<2, 256, 0, stream>>>(mb2 + (size_t)l * EMB, EMB, b2p + (size_t)l * HP, HP);
    }
    k_tconv<<<256, 256, 0, stream>>>(fw, 500, 512, fwt, 512, 512);
    k_tconv<<<128, 256, 0, stream>>>(pw1, 512, 256, p1t, 512, 256);
    k_tconv<<<64, 256, 0, stream>>>(pw2, 256, 256, p2t, 256, 256);

    // node embedding + graph structure prep
    k_embed<<<NN, 320, 0, stream>>>(x, ae1, ae2, aw3, ab3, h);
    k_init<<<(NN + 255) / 256, 256, 0, stream>>>(stat, cursor);
    k_estats<<<(EE + 255) / 256, 256, 0, stream>>>(ei, ea, stat);
    k_scan<<<1, 1024, 0, stream>>>(stat, rowptr);
    k_fill<<<(EE + 255) / 256, 256, 0, stream>>>(ei, rowptr, cursor, col);

    for (int l = 0; l < NLAYER; l++) {
        k_agg<<<MPAD, 320, 0, stream>>>(h, stat, rowptr, col, ee1, ee2, ew3, eb3, agg, l);
        k_gemm<<<dim3(MPAD / 128, YP / 64), 256, 0, stream>>>(
            agg, HP, w1t + (size_t)l * YP * HP, HP, b1p + (size_t)l * YP, y1, nullptr, YP, HP, 1);
        k_gemm<<<dim3(MPAD / 128, HP / 64), 256, 0, stream>>>(
            y1, YP, w2t + (size_t)l * HP * YP, YP, b2p + (size_t)l * HP, nullptr, h2f, HP, YP, 0);
        k_bn_stats<<<256, 320, 0, stream>>>(h2f, psum, psq);
        k_bn_final<<<1, 320, 0, stream>>>(psum, psq, bng, bnb, scl, sft, l);
        k_bn_apply<<<NN, 320, 0, stream>>>(h2f, scl, sft,
            (l < NLAYER - 1) ? h : out, (l < NLAYER - 1) ? 1 : 0);
    }

    k_pool_init<<<(BG * EMB + 255) / 256, 256, 0, stream>>>(pooled, cntB);
    k_pool_acc<<<NN, 320, 0, stream>>>(out, batch, pooled, cntB);
    k_head_in<<<MHEAD, 512, 0, stream>>>(pooled, cntB, x_add, hin);
    k_gemm<<<dim3(MHEAD / 128, 512 / 64), 256, 0, stream>>>(hin, 512, fwt, 512, fb, g1, nullptr, 512, 512, 0);
    k_gemm<<<dim3(MHEAD / 128, 256 / 64), 256, 0, stream>>>(g1, 512, p1t, 512, pb1, g2, nullptr, 256, 512, 2);
    k_gemm<<<dim3(MHEAD / 128, 256 / 64), 256, 0, stream>>>(g2, 256, p2t, 256, pb2, g3, nullptr, 256, 256, 2);
    k_pred<<<BG, 64, 0, stream>>>(g3, pw3, pb3, out + (size_t)NN * EMB);
}

// Round 3
// 2035.232 us; speedup vs baseline: 1.3551x; 1.3551x over previous
//
#include <hip/hip_runtime.h>
#include <stdint.h>

#define NN 50000
#define EE 800000
#define BG 2000
#define EMB 300
#define HP 320
#define YP 640
#define MPAD 50048
#define MHEAD 2048
#define NLAYER 5

typedef __attribute__((ext_vector_type(8))) _Float16 f16x8;
typedef __attribute__((ext_vector_type(4))) float f32x4;

__device__ __forceinline__ _Float16 f2h(float f) { return (_Float16)f; }

// ---------- all weight transposes+convert in one launch
// dst[Np][Kp] (f16) = src[K][Ns]^T, zero pad
__global__ void k_tconv_all(const float* __restrict__ mw1, const float* __restrict__ mw2,
        const float* __restrict__ fw, const float* __restrict__ pw1, const float* __restrict__ pw2,
        _Float16* __restrict__ w1t, _Float16* __restrict__ w2t, _Float16* __restrict__ fwt,
        _Float16* __restrict__ p1t, _Float16* __restrict__ p2t) {
    int job = blockIdx.x;
    const float* src; _Float16* dst; int K, Ns, Kp, Np;
    if (job < 5)       { src = mw1 + (size_t)job * EMB * 2 * EMB; dst = w1t + (size_t)job * YP * HP; K = EMB; Ns = 2 * EMB; Kp = HP; Np = YP; }
    else if (job < 10) { int l = job - 5; src = mw2 + (size_t)l * 2 * EMB * EMB; dst = w2t + (size_t)l * HP * YP; K = 2 * EMB; Ns = EMB; Kp = YP; Np = HP; }
    else if (job == 10){ src = fw;  dst = fwt; K = 500; Ns = 512; Kp = 512; Np = 512; }
    else if (job == 11){ src = pw1; dst = p1t; K = 512; Ns = 256; Kp = 512; Np = 256; }
    else               { src = pw2; dst = p2t; K = 256; Ns = 256; Kp = 256; Np = 256; }
    int total = Kp * Np;
    for (int idx = blockIdx.y * 256 + threadIdx.x; idx < total; idx += gridDim.y * 256) {
        int n = idx / Kp, k = idx - n * Kp;
        float v = (n < Ns && k < K) ? src[(size_t)k * Ns + n] : 0.f;
        dst[idx] = f2h(v);
    }
}

__global__ void k_padbias_all(const float* __restrict__ mb1, const float* __restrict__ mb2,
                              float* __restrict__ b1p, float* __restrict__ b2p) {
    int idx = blockIdx.x * 256 + threadIdx.x;
    if (idx < NLAYER * YP) {
        int l = idx / YP, c = idx - l * YP;
        b1p[idx] = (c < 2 * EMB) ? mb1[(size_t)l * 2 * EMB + c] : 0.f;
    } else if (idx < NLAYER * YP + NLAYER * HP) {
        int j = idx - NLAYER * YP; int l = j / HP, c = j - l * HP;
        b2p[j] = (c < EMB) ? mb2[(size_t)l * EMB + c] : 0.f;
    }
}

// ---------- zero/init scratch that must be clean each launch
__global__ void k_prep(int* __restrict__ deg, int* __restrict__ cursor,
                       float* __restrict__ psum, float* __restrict__ psq,
                       float* __restrict__ scl, float* __restrict__ sft) {
    int i = blockIdx.x * blockDim.x + threadIdx.x;
    if (i < NN) { deg[i] = 0; cursor[i] = 0; }
    if (i < HP) { psum[i] = 0.f; psq[i] = 0.f; scl[i] = 1.f; sft[i] = 0.f; }  // slot 0 = identity
}

// ---------- node embedding -> h2 (f16, padded rows)
__global__ __launch_bounds__(320) void k_embed(const int* __restrict__ x,
        const float* __restrict__ ae1, const float* __restrict__ ae2,
        const float* __restrict__ aw3, const float* __restrict__ ab3,
        _Float16* __restrict__ h2) {
    int i = blockIdx.x, tid = threadIdx.x;
    __shared__ int sx[42];
    if (tid < 42) sx[tid] = x[(size_t)i * 42 + tid];
    __syncthreads();
    if (tid < EMB) {
        float v = ab3[tid] + ae1[(size_t)sx[0] * EMB + tid] + ae2[(size_t)sx[1] * EMB + tid];
        #pragma unroll 8
        for (int j = 0; j < 40; j++) v += (float)sx[2 + j] * aw3[(size_t)j * EMB + tid];
        h2[(size_t)i * HP + tid] = f2h(v);
    } else {
        h2[(size_t)i * HP + tid] = (_Float16)0.f;
    }
}

// ---------- degree histogram (1 atomic per edge)
__global__ void k_deg(const int* __restrict__ ei, int* __restrict__ deg) {
    int e = blockIdx.x * blockDim.x + threadIdx.x;
    if (e < EE) atomicAdd(&deg[ei[EE + e]], 1);
}

// ---------- exclusive scan of deg -> rowptr
__global__ __launch_bounds__(1024) void k_scan(const int* __restrict__ deg,
                                               int* __restrict__ rowptr) {
    __shared__ int part[1024];
    int t = threadIdx.x;
    const int chunk = (NN + 1023) / 1024;
    int i0 = t * chunk;
    int i1 = min(i0 + chunk, NN);
    int s = 0;
    for (int i = i0; i < i1; i++) s += deg[i];
    part[t] = s;
    __syncthreads();
    for (int off = 1; off < 1024; off <<= 1) {
        int v = part[t];
        int u = (t >= off) ? part[t - off] : 0;
        __syncthreads();
        part[t] = v + u;
        __syncthreads();
    }
    int run = (t > 0) ? part[t - 1] : 0;
    for (int i = i0; i < i1; i++) { rowptr[i] = run; run += deg[i]; }
    if (t == 1023) rowptr[NN] = part[1023];
}

// ---------- CSR fill: col=src, eattr=packed edge attrs (2b each: ea0, ea1, eaf[0..7])
__global__ void k_fill(const int* __restrict__ ei, const int* __restrict__ ea,
                       const int* __restrict__ rowptr, int* __restrict__ cursor,
                       int* __restrict__ col, unsigned int* __restrict__ eattr) {
    int e = blockIdx.x * blockDim.x + threadIdx.x;
    if (e < EE) {
        int d = ei[EE + e];
        int pos = rowptr[d] + atomicAdd(&cursor[d], 1);
        col[pos] = ei[e];
        unsigned int p = (unsigned int)ea[e * 10 + 0] | ((unsigned int)ea[e * 10 + 1] << 2);
        #pragma unroll
        for (int j = 0; j < 8; j++) p |= (unsigned int)ea[e * 10 + 2 + j] << (4 + 2 * j);
        eattr[pos] = p;
    }
}

// ---------- per-node edge-attr stats from CSR (no atomics); 1 wave per node
// stat[i][0..5]=cnt(ea0) [4]=self, [6..9]=cnt(ea1), [10..17]=sum(eaf), [18]=deg incl self
__global__ __launch_bounds__(256) void k_stats(const int* __restrict__ rowptr,
        const unsigned int* __restrict__ eattr, int* __restrict__ stat) {
    int node = blockIdx.x * 4 + (threadIdx.x >> 6);
    int lane = threadIdx.x & 63;
    if (node >= NN) return;
    int beg = rowptr[node], end = rowptr[node + 1];
    int c0 = 0, c1 = 0, c2 = 0, d1 = 0, d2 = 0;
    int s[8] = {0, 0, 0, 0, 0, 0, 0, 0};
    for (int e = beg + lane; e < end; e += 64) {
        unsigned int p = eattr[e];
        unsigned int a0 = p & 3u, a1 = (p >> 2) & 3u;
        c0 += (a0 == 0); c1 += (a0 == 1); c2 += (a0 == 2);
        d1 += (a1 == 1); d2 += (a1 == 2);
        #pragma unroll
        for (int j = 0; j < 8; j++) s[j] += (int)((p >> (4 + 2 * j)) & 3u);
    }
    #pragma unroll
    for (int off = 32; off; off >>= 1) {
        c0 += __shfl_down(c0, off); c1 += __shfl_down(c1, off); c2 += __shfl_down(c2, off);
        d1 += __shfl_down(d1, off); d2 += __shfl_down(d2, off);
        #pragma unroll
        for (int j = 0; j < 8; j++) s[j] += __shfl_down(s[j], off);
    }
    if (lane == 0) {
        int dg = end - beg;
        int* st = stat + (size_t)node * 20;
        st[0] = c0; st[1] = c1; st[2] = c2; st[3] = 0; st[4] = 1; st[5] = 0;
        st[6] = dg - d1 - d2 + 1; st[7] = d1; st[8] = d2; st[9] = 0;
        #pragma unroll
        for (int j = 0; j < 8; j++) st[10 + j] = s[j];
        st[18] = dg + 1; st[19] = 0;
    }
}

// ---------- fused BN(prev layer) + message aggregation
// agg[i] = const(stat) + sum_{s in {i} ∪ in(i)} act(h2[s]*scl+sft)
__global__ __launch_bounds__(320) void k_agg(const _Float16* __restrict__ h2,
        const float* __restrict__ scl, const float* __restrict__ sft, int dorelu,
        const int* __restrict__ stat, const int* __restrict__ rowptr,
        const int* __restrict__ col,
        const float* __restrict__ ee1, const float* __restrict__ ee2,
        const float* __restrict__ ew3, const float* __restrict__ eb3,
        _Float16* __restrict__ agg, int layer) {
    int i = blockIdx.x;
    int tid = threadIdx.x;
    if (i >= NN) { agg[(size_t)i * HP + tid] = (_Float16)0.f; return; }
    __shared__ int ss[20];
    if (tid < 20) ss[tid] = stat[(size_t)i * 20 + tid];
    float sc_ = scl[tid], sf_ = sft[tid];
    __syncthreads();
    int c = tid;
    bool act = c < EMB;
    float acc = 0.f;
    if (act) {
        const float* e1 = ee1 + (size_t)layer * 6 * EMB;
        const float* e2 = ee2 + (size_t)layer * 4 * EMB;
        const float* w3 = ew3 + (size_t)layer * 8 * EMB;
        float v = eb3[(size_t)layer * EMB + c] * (float)ss[18];
        #pragma unroll
        for (int k = 0; k < 6; k++) v += (float)ss[k] * e1[k * EMB + c];
        #pragma unroll
        for (int k = 0; k < 4; k++) v += (float)ss[6 + k] * e2[k * EMB + c];
        #pragma unroll
        for (int j = 0; j < 8; j++) v += (float)ss[10 + j] * w3[j * EMB + c];
        // self term
        float hv = (float)h2[(size_t)i * HP + c];
        float t = fmaf(hv, sc_, sf_);
        if (dorelu) t = fmaxf(t, 0.f);
        acc = v + t;
        int beg = rowptr[i], end = rowptr[i + 1];
        #pragma unroll 4
        for (int e = beg; e < end; ++e) {
            int sid = col[e];
            float v2 = (float)h2[(size_t)sid * HP + c];
            float t2 = fmaf(v2, sc_, sf_);
            if (dorelu) t2 = fmaxf(t2, 0.f);
            acc += t2;
        }
    }
    agg[(size_t)i * HP + tid] = act ? f2h(acc) : (_Float16)0.f;
}

// ---------- f16 MFMA GEMM: C = act(A[M][lda] @ Wt^T + bias), f16 out
// optional per-column stats (sum, sumsq over rows<NN) accumulated via atomics
__global__ __launch_bounds__(256) void k_gemm(const _Float16* __restrict__ A, int lda,
        const _Float16* __restrict__ Wt, int ldw, const float* __restrict__ bias,
        _Float16* __restrict__ C, int ldc, int K, int act,
        float* __restrict__ psum, float* __restrict__ psq) {
    __shared__ _Float16 As[128 * 32];
    __shared__ _Float16 Bs[64 * 32];
    int tid = threadIdx.x;
    int lane = tid & 63;
    int wid = tid >> 6;
    int wr = wid >> 1, wc = wid & 1;
    size_t rowBase = (size_t)blockIdx.x * 128;
    int colBase = blockIdx.y * 64;

    int srow = tid >> 2;
    int schunk = tid & 3;
    const _Float16* Ab  = A + (rowBase + srow) * (size_t)lda + (schunk << 3);
    const _Float16* Ab2 = Ab + (size_t)64 * lda;
    const _Float16* Bb  = Wt + ((size_t)colBase + srow) * ldw + (schunk << 3);
    int swz = ((schunk ^ ((srow >> 1) & 3)) << 3);
    int wa0 = srow * 32 + swz;
    int wa1 = wa0 + 64 * 32;
    int wb  = wa0;

    uint4 ra0 = *(const uint4*)Ab;
    uint4 ra1 = *(const uint4*)Ab2;
    uint4 rb  = *(const uint4*)Bb;

    int lr = lane & 15, lg = lane >> 4;
    int lswz = (lr >> 1) & 3;
    int aoff[4], boff[2];
    #pragma unroll
    for (int m = 0; m < 4; m++) { int r = wr * 64 + m * 16 + lr; aoff[m] = r * 32 + ((lg ^ lswz) << 3); }
    #pragma unroll
    for (int n = 0; n < 2; n++) { int r = wc * 32 + n * 16 + lr; boff[n] = r * 32 + ((lg ^ lswz) << 3); }

    f32x4 acc[4][2];
    #pragma unroll
    for (int m = 0; m < 4; m++)
        #pragma unroll
        for (int n = 0; n < 2; n++) acc[m][n] = (f32x4){0.f, 0.f, 0.f, 0.f};

    int nk = K >> 5;
    for (int kt = 0; kt < nk; ++kt) {
        __syncthreads();
        *(uint4*)&As[wa0] = ra0;
        *(uint4*)&As[wa1] = ra1;
        *(uint4*)&Bs[wb]  = rb;
        __syncthreads();
        if (kt + 1 < nk) {
            int o = (kt + 1) << 5;
            ra0 = *(const uint4*)(Ab + o);
            ra1 = *(const uint4*)(Ab2 + o);
            rb  = *(const uint4*)(Bb + o);
        }
        f16x8 af[4], bfr[2];
        #pragma unroll
        for (int m = 0; m < 4; m++) af[m] = *(const f16x8*)&As[aoff[m]];
        #pragma unroll
        for (int n = 0; n < 2; n++) bfr[n] = *(const f16x8*)&Bs[boff[n]];
        #pragma unroll
        for (int m = 0; m < 4; m++)
            #pragma unroll
            for (int n = 0; n < 2; n++)
                acc[m][n] = __builtin_amdgcn_mfma_f32_16x16x32_f16(af[m], bfr[n], acc[m][n], 0, 0, 0);
    }

    bool dostats = (psum != nullptr);
    float sstat[2] = {0.f, 0.f}, qstat[2] = {0.f, 0.f};
    #pragma unroll
    for (int m = 0; m < 4; m++) {
        #pragma unroll
        for (int n = 0; n < 2; n++) {
            int colg = colBase + wc * 32 + n * 16 + lr;
            float bv = bias[colg];
            #pragma unroll
            for (int r = 0; r < 4; r++) {
                size_t rowg = rowBase + wr * 64 + m * 16 + lg * 4 + r;
                float v = acc[m][n][r] + bv;
                if (act == 1) v = fmaxf(v, 0.f);
                else if (act == 2) v = (v > 0.f) ? v + log1pf(expf(-v)) : log1pf(expf(v));
                C[rowg * ldc + colg] = f2h(v);
                if (dostats && rowg < NN) { sstat[n] += v; qstat[n] += v * v; }
            }
        }
    }
    if (dostats) {
        #pragma unroll
        for (int n = 0; n < 2; n++) {
            float s_ = sstat[n], q_ = qstat[n];
            s_ += __shfl_xor(s_, 16); q_ += __shfl_xor(q_, 16);
            s_ += __shfl_xor(s_, 32); q_ += __shfl_xor(q_, 32);
            if (lane < 16) {
                int colg = colBase + wc * 32 + n * 16 + lr;
                atomicAdd(&psum[colg], s_);
                atomicAdd(&psq[colg], q_);
            }
        }
    }
}

// ---------- BN finalize: scl/sft for slot layer+1; re-zero psum/psq
__global__ __launch_bounds__(320) void k_bn_final(float* __restrict__ psum,
        float* __restrict__ psq, const float* __restrict__ bng,
        const float* __restrict__ bnb, float* __restrict__ scl, float* __restrict__ sft,
        int layer) {
    int c = threadIdx.x;
    float s = psum[c], q = psq[c];
    float* so = scl + (size_t)(layer + 1) * HP;
    float* fo = sft + (size_t)(layer + 1) * HP;
    if (c < EMB) {
        float mu = s / (float)NN;
        float var = q / (float)NN - mu * mu;
        float rstd = rsqrtf(var + 1e-5f);
        float g = bng[(size_t)layer * EMB + c] * rstd;
        so[c] = g;
        fo[c] = bnb[(size_t)layer * EMB + c] - mu * g;
    } else { so[c] = 0.f; fo[c] = 0.f; }
    psum[c] = 0.f; psq[c] = 0.f;
}

// ---------- final BN apply -> out (f32 h_node)
__global__ __launch_bounds__(320) void k_bn_apply(const _Float16* __restrict__ h2,
        const float* __restrict__ scl, const float* __restrict__ sft,
        float* __restrict__ out) {
    int i = blockIdx.x, c = threadIdx.x;
    if (c < EMB)
        out[(size_t)i * EMB + c] = fmaf((float)h2[(size_t)i * HP + c], scl[c], sft[c]);
}

// ---------- pooling: batch is sorted -> per-graph contiguous segment, no atomics
__global__ __launch_bounds__(320) void k_pool(const float* __restrict__ hn,
        const int* __restrict__ batch, float* __restrict__ pooled) {
    __shared__ int sb[2];
    if (threadIdx.x < 2) {
        int target = blockIdx.x + threadIdx.x;
        int lo = 0, hi = NN;
        while (lo < hi) { int mid = (lo + hi) >> 1; if (batch[mid] < target) lo = mid + 1; else hi = mid; }
        sb[threadIdx.x] = lo;
    }
    __syncthreads();
    int s = sb[0], e = sb[1], c = threadIdx.x;
    if (c < EMB) {
        float acc = 0.f;
        for (int i = s; i < e; i++) acc += hn[(size_t)i * EMB + c];
        float inv = 1.f / (float)max(e - s, 1);
        pooled[(size_t)blockIdx.x * EMB + c] = acc * inv;
    }
}

__global__ __launch_bounds__(512) void k_head_in(const float* __restrict__ pooled,
        const float* __restrict__ x_add, _Float16* __restrict__ hin) {
    int b = blockIdx.x, c = threadIdx.x;
    float v = 0.f;
    if (b < BG) {
        if (c < EMB) v = pooled[(size_t)b * EMB + c];
        else if (c < EMB + 200) v = x_add[(size_t)b * 200 + (c - EMB)];
    }
    hin[(size_t)b * 512 + c] = f2h(v);
}

__global__ __launch_bounds__(64) void k_pred(const _Float16* __restrict__ g3,
        const float* __restrict__ pw3, const float* __restrict__ pb3, float* __restrict__ out) {
    int row = blockIdx.x;
    int lane = threadIdx.x;
    float s = 0.f;
    #pragma unroll
    for (int t = 0; t < 4; t++) {
        int k = lane * 4 + t;
        s += (float)g3[(size_t)row * 256 + k] * pw3[k];
    }
    #pragma unroll
    for (int off = 32; off; off >>= 1) s += __shfl_down(s, off);
    if (lane == 0) out[row] = s + pb3[0];
}

extern "C" void kernel_launch(void* const* d_in, const int* in_sizes, int n_in,
                              void* d_out, int out_size, void* d_ws, size_t ws_size,
                              hipStream_t stream) {
    const int*   x     = (const int*)d_in[0];
    const int*   ei    = (const int*)d_in[1];
    const int*   ea    = (const int*)d_in[2];
    const int*   batch = (const int*)d_in[3];
    const float* x_add = (const float*)d_in[4];
    const float* ae1   = (const float*)d_in[5];
    const float* ae2   = (const float*)d_in[6];
    const float* aw3   = (const float*)d_in[7];
    const float* ab3   = (const float*)d_in[8];
    const float* ee1   = (const float*)d_in[9];
    const float* ee2   = (const float*)d_in[10];
    const float* ew3   = (const float*)d_in[11];
    const float* eb3   = (const float*)d_in[12];
    const float* mw1   = (const float*)d_in[13];
    const float* mb1   = (const float*)d_in[14];
    const float* mw2   = (const float*)d_in[15];
    const float* mb2   = (const float*)d_in[16];
    const float* bng   = (const float*)d_in[17];
    const float* bnb   = (const float*)d_in[18];
    const float* fw    = (const float*)d_in[19];
    const float* fb    = (const float*)d_in[20];
    const float* pw1   = (const float*)d_in[21];
    const float* pb1   = (const float*)d_in[22];
    const float* pw2   = (const float*)d_in[23];
    const float* pb2   = (const float*)d_in[24];
    const float* pw3   = (const float*)d_in[25];
    const float* pb3   = (const float*)d_in[26];
    (void)in_sizes; (void)n_in; (void)out_size; (void)ws_size;
    float* out = (float*)d_out;

    char* p = (char*)d_ws;
    auto take = [&](size_t bytes) -> char* {
        char* r = p; p += (bytes + 255) & ~(size_t)255; return r;
    };
    _Float16*  h2   = (_Float16*)take((size_t)MPAD * HP * 2);
    _Float16*  agg  = (_Float16*)take((size_t)MPAD * HP * 2);
    _Float16*  y1   = (_Float16*)take((size_t)MPAD * YP * 2);
    _Float16*  w1t  = (_Float16*)take((size_t)NLAYER * YP * HP * 2);
    _Float16*  w2t  = (_Float16*)take((size_t)NLAYER * HP * YP * 2);
    _Float16*  fwt  = (_Float16*)take((size_t)512 * 512 * 2);
    _Float16*  p1t  = (_Float16*)take((size_t)256 * 512 * 2);
    _Float16*  p2t  = (_Float16*)take((size_t)256 * 256 * 2);
    float* b1p    = (float*)take((size_t)NLAYER * YP * 4);
    float* b2p    = (float*)take((size_t)NLAYER * HP * 4);
    int* deg      = (int*)take((size_t)NN * 4);
    int* cursor   = (int*)take((size_t)NN * 4);
    int* rowptr   = (int*)take((size_t)(NN + 1) * 4);
    int* col      = (int*)take((size_t)EE * 4);
    unsigned int* eattr = (unsigned int*)take((size_t)EE * 4);
    int* stat     = (int*)take((size_t)NN * 20 * 4);
    float* psum   = (float*)take((size_t)HP * 4);
    float* psq    = (float*)take((size_t)HP * 4);
    float* scl    = (float*)take((size_t)(NLAYER + 1) * HP * 4);
    float* sft    = (float*)take((size_t)(NLAYER + 1) * HP * 4);
    float* pooled = (float*)take((size_t)BG * EMB * 4);
    // head buffers alias y1 (dead after layer loop)
    char* hb = (char*)y1;
    _Float16* hin = (_Float16*)hb;  hb += (size_t)MHEAD * 512 * 2;
    _Float16* g1  = (_Float16*)hb;  hb += (size_t)MHEAD * 512 * 2;
    _Float16* g2  = (_Float16*)hb;  hb += (size_t)MHEAD * 256 * 2;
    _Float16* g3  = (_Float16*)hb;

    k_prep<<<(NN + 255) / 256, 256, 0, stream>>>(deg, cursor, psum, psq, scl, sft);
    k_tconv_all<<<dim3(13, 1024), 256, 0, stream>>>(mw1, mw2, fw, pw1, pw2, w1t, w2t, fwt, p1t, p2t);
    k_padbias_all<<<19, 256, 0, stream>>>(mb1, mb2, b1p, b2p);
    k_embed<<<NN, 320, 0, stream>>>(x, ae1, ae2, aw3, ab3, h2);
    k_deg<<<(EE + 255) / 256, 256, 0, stream>>>(ei, deg);
    k_scan<<<1, 1024, 0, stream>>>(deg, rowptr);
    k_fill<<<(EE + 255) / 256, 256, 0, stream>>>(ei, ea, rowptr, cursor, col, eattr);
    k_stats<<<(NN + 3) / 4, 256, 0, stream>>>(rowptr, eattr, stat);

    for (int l = 0; l < NLAYER; l++) {
        k_agg<<<MPAD, 320, 0, stream>>>(h2, scl + (size_t)l * HP, sft + (size_t)l * HP,
            (l > 0) ? 1 : 0, stat, rowptr, col, ee1, ee2, ew3, eb3, agg, l);
        k_gemm<<<dim3(MPAD / 128, YP / 64), 256, 0, stream>>>(
            agg, HP, w1t + (size_t)l * YP * HP, HP, b1p + (size_t)l * YP, y1, YP, HP, 1,
            nullptr, nullptr);
        k_gemm<<<dim3(MPAD / 128, HP / 64), 256, 0, stream>>>(
            y1, YP, w2t + (size_t)l * HP * YP, YP, b2p + (size_t)l * HP, h2, HP, YP, 0,
            psum, psq);
        k_bn_final<<<1, 320, 0, stream>>>(psum, psq, bng, bnb, scl, sft, l);
    }
    k_bn_apply<<<NN, 320, 0, stream>>>(h2, scl + (size_t)NLAYER * HP, sft + (size_t)NLAYER * HP, out);

    k_pool<<<BG, 320, 0, stream>>>(out, batch, pooled);
    k_head_in<<<MHEAD, 512, 0, stream>>>(pooled, x_add, hin);
    k_gemm<<<dim3(MHEAD / 128, 512 / 64), 256, 0, stream>>>(hin, 512, fwt, 512, fb, g1, 512, 512, 0, nullptr, nullptr);
    k_gemm<<<dim3(MHEAD / 128, 256 / 64), 256, 0, stream>>>(g1, 512, p1t, 512, pb1, g2, 256, 512, 2, nullptr, nullptr);
    k_gemm<<<dim3(MHEAD / 128, 256 / 64), 256, 0, stream>>>(g2, 256, p2t, 256, pb2, g3, 256, 256, 2, nullptr, nullptr);
    k_pred<<<BG, 64, 0, stream>>>(g3, pw3, pb3, out + (size_t)NN * EMB);
}